// Round 1
// baseline (308.107 us; speedup 1.0000x reference)
//
#include <hip/hip_runtime.h>

typedef __bf16 bf16;
typedef __bf16 bf16x8 __attribute__((ext_vector_type(8)));
typedef __bf16 bf16x4 __attribute__((ext_vector_type(4)));
typedef float  f32x4  __attribute__((ext_vector_type(4)));

#define MFMA16(a, b, c) __builtin_amdgcn_mfma_f32_16x16x32_bf16((a), (b), (c), 0, 0, 0)

// async global->LDS, 16B per lane, LDS dst = wave-uniform base + lane*16
__device__ __forceinline__ void gload_lds16(const bf16* g, bf16* l) {
  __builtin_amdgcn_global_load_lds(
      (const __attribute__((address_space(1))) void*)g,
      (__attribute__((address_space(3))) void*)l, 16, 0, 0);
}

// ---------------- prep kernels ----------------

// fp32 -> bf16, 4 elems/thread
__global__ __launch_bounds__(256) void cast_bf16_kernel(
    const float* __restrict__ in, bf16* __restrict__ out, int n4) {
  int i = blockIdx.x * 256 + threadIdx.x;
  if (i < n4) {
    float4 v = reinterpret_cast<const float4*>(in)[i];
    bf16x4 o;
    o[0] = (bf16)v.x; o[1] = (bf16)v.y; o[2] = (bf16)v.z; o[3] = (bf16)v.w;
    reinterpret_cast<bf16x4*>(out)[i] = o;
  }
}

// W (K,N) fp32 -> Wt (N,K) bf16, 64x64 LDS tiles, stride 66 (2-way banks, free)
__global__ __launch_bounds__(256) void transpose_cast_kernel(
    const float* __restrict__ W, bf16* __restrict__ Wt, int K, int N) {
  __shared__ bf16 tile[64 * 66];
  const int k0 = blockIdx.y * 64, n0 = blockIdx.x * 64;
  const int c = threadIdx.x & 63, rb = threadIdx.x >> 6;
#pragma unroll
  for (int p = 0; p < 16; ++p) {
    int r = p * 4 + rb;  // k-local
    tile[c * 66 + r] = (bf16)W[(long)(k0 + r) * N + n0 + c];
  }
  __syncthreads();
#pragma unroll
  for (int p = 0; p < 16; ++p) {
    int r = p * 4 + rb;  // n-local
    Wt[(long)(n0 + r) * K + k0 + c] = tile[r * 66 + c];
  }
}

// ---------------- GEMM: C(M,N) = A(M,K) @ Bt(N,K)^T, m97 structure ----------------
// 128x128 tile, BK=64, 256 threads (4 waves, 2x2), acc 4x4 frags/wave.
// EPI 0: QKV epilogue (bias, Q pre-scaled by 0.125*log2e, scatter Q/K (b,h,t,d), V -> (b,h,d,t))
// EPI 1: out-proj epilogue (bias, fp32 store)
template <int EPI>
__global__ __launch_bounds__(256, 2) void gemm_bt(
    const bf16* __restrict__ A, const bf16* __restrict__ Bt,
    const float* __restrict__ bias, bf16* __restrict__ oQ,
    bf16* __restrict__ oK, bf16* __restrict__ oVT, float* __restrict__ oC,
    int K) {
  __shared__ bf16 As[128 * 64];
  __shared__ bf16 Bs[128 * 64];
  const int tid = threadIdx.x, lane = tid & 63, wid = tid >> 6;
  const int wr = wid >> 1, wc = wid & 1;
  const int brow = blockIdx.x * 128, bcol = blockIdx.y * 128;
  const int srow = lane >> 3, scol8 = (lane & 7) * 8;
  const int c15 = lane & 15, g = lane >> 4;

  f32x4 acc[4][4];
#pragma unroll
  for (int m = 0; m < 4; ++m)
#pragma unroll
    for (int n = 0; n < 4; ++n) acc[m][n] = f32x4{0.f, 0.f, 0.f, 0.f};

  const bf16* Ab = A + (long)brow * K + scol8;
  const bf16* Bb = Bt + (long)bcol * K + scol8;

  for (int k0 = 0; k0 < K; k0 += 64) {
    // stage A,B tiles: 16 chunks each of 8 rows x 128B; chunk c = wid*4+i
#pragma unroll
    for (int i = 0; i < 4; ++i) {
      int c = wid * 4 + i;
      int row = c * 8 + srow;
      gload_lds16(Ab + (long)row * K + k0, &As[c * 512]);
    }
#pragma unroll
    for (int i = 0; i < 4; ++i) {
      int c = wid * 4 + i;
      int row = c * 8 + srow;
      gload_lds16(Bb + (long)row * K + k0, &Bs[c * 512]);
    }
    __syncthreads();
#pragma unroll
    for (int kk = 0; kk < 64; kk += 32) {
      bf16x8 a[4], b[4];
#pragma unroll
      for (int m = 0; m < 4; ++m)
        a[m] = *(const bf16x8*)&As[(wr * 64 + m * 16 + c15) * 64 + kk + g * 8];
#pragma unroll
      for (int n = 0; n < 4; ++n)
        b[n] = *(const bf16x8*)&Bs[(wc * 64 + n * 16 + c15) * 64 + kk + g * 8];
#pragma unroll
      for (int m = 0; m < 4; ++m)
#pragma unroll
        for (int n = 0; n < 4; ++n)
          acc[m][n] = MFMA16(a[m], b[n], acc[m][n]);
    }
    __syncthreads();
  }

  // epilogue. C/D layout: col = c15, row = g*4 + r (m89-verified)
#pragma unroll
  for (int n = 0; n < 4; ++n) {
    const int col = bcol + wc * 64 + n * 16 + c15;
    const float bv = bias[col];
    if (EPI == 0) {
      const int which = col >> 10, wi = col & 1023, h = wi >> 6, d = wi & 63;
      const float sc = (which == 0) ? 0.18033688011112042f : 1.0f;  // 0.125*log2(e) for Q
#pragma unroll
      for (int m = 0; m < 4; ++m) {
        const int row0 = brow + wr * 64 + m * 16 + g * 4;
        const int bb = row0 >> 11, t0 = row0 & 2047;
        const long hb = bb * 16 + h;
        if (which == 2) {
          bf16x4 pv;
#pragma unroll
          for (int r = 0; r < 4; ++r) pv[r] = (bf16)(acc[m][n][r] + bv);
          *(bf16x4*)&oVT[(hb * 64 + d) * 2048 + t0] = pv;  // V transposed: (b,h,d,t)
        } else {
          bf16* dst = ((which == 0) ? oQ : oK) + (hb * 2048 + t0) * 64 + d;
#pragma unroll
          for (int r = 0; r < 4; ++r)
            dst[(long)r * 64] = (bf16)((acc[m][n][r] + bv) * sc);
        }
      }
    } else {
#pragma unroll
      for (int m = 0; m < 4; ++m) {
        const long row = brow + wr * 64 + m * 16 + g * 4;
#pragma unroll
        for (int r = 0; r < 4; ++r) oC[(row + r) * 1024 + col] = acc[m][n][r] + bv;
      }
    }
  }
}

// ---------------- flash attention ----------------
// grid (32 q-tiles, 32 bh). 4 waves x 16 queries. KBLK=64. K/V direct from
// global (L1/L2-resident per bh). Q pre-scaled by 0.125*log2e -> exp2 softmax.
__global__ __launch_bounds__(256, 4) void attn_kernel(
    const bf16* __restrict__ Q, const bf16* __restrict__ K,
    const bf16* __restrict__ VT, const int* __restrict__ mask,
    bf16* __restrict__ Aout) {
  __shared__ bf16 Plds[4][16 * 72];  // per-wave P tile, stride 72 (2-way banks)
  const int tid = threadIdx.x, lane = tid & 63, w = tid >> 6;
  const int c15 = lane & 15, g = lane >> 4;
  const int qt = blockIdx.x, bh = blockIdx.y;
  const int b = bh >> 4, h = bh & 15;
  const int q0 = qt * 64 + w * 16;

  const bf16* Qp = Q + ((long)bh * 2048 + q0) * 64;
  const bf16x8 aq0 = *(const bf16x8*)(Qp + c15 * 64 + g * 8);
  const bf16x8 aq1 = *(const bf16x8*)(Qp + c15 * 64 + 32 + g * 8);

  f32x4 o[4];
  float mrun[4], lrun[4];
#pragma unroll
  for (int n = 0; n < 4; ++n) o[n] = f32x4{0.f, 0.f, 0.f, 0.f};
#pragma unroll
  for (int r = 0; r < 4; ++r) { mrun[r] = -1e30f; lrun[r] = 0.f; }

  const bf16* Kbh = K + (long)bh * 2048 * 64;
  const bf16* Vbh = VT + (long)bh * 64 * 2048;
  const int* mb = mask + b * 2048;
  bf16* pl = &Plds[w][0];

  for (int kt = 0; kt < 32; ++kt) {
    const int kbase = kt * 64;
    // S = Q @ K^T (already in log2 units): col=key=c15, row=query=g*4+r
    f32x4 s[4];
#pragma unroll
    for (int kf = 0; kf < 4; ++kf) {
      const bf16* Kp = Kbh + (long)(kbase + kf * 16 + c15) * 64 + g * 8;
      bf16x8 bk0 = *(const bf16x8*)(Kp);
      bf16x8 bk1 = *(const bf16x8*)(Kp + 32);
      f32x4 z = f32x4{0.f, 0.f, 0.f, 0.f};
      z = MFMA16(aq0, bk0, z);
      z = MFMA16(aq1, bk1, z);
      s[kf] = z;
    }
    // mask (key-wise)
#pragma unroll
    for (int kf = 0; kf < 4; ++kf) {
      if (mb[kbase + kf * 16 + c15] == 0) {
#pragma unroll
        for (int r = 0; r < 4; ++r) s[kf][r] = -1e30f;
      }
    }
    // wave-parallel row max (16-lane butterfly; rows live in g-groups)
    float pm[4];
#pragma unroll
    for (int r = 0; r < 4; ++r)
      pm[r] = fmaxf(fmaxf(s[0][r], s[1][r]), fmaxf(s[2][r], s[3][r]));
#pragma unroll
    for (int off = 1; off < 16; off <<= 1)
#pragma unroll
      for (int r = 0; r < 4; ++r) pm[r] = fmaxf(pm[r], __shfl_xor(pm[r], off));

    float scale[4];
#pragma unroll
    for (int r = 0; r < 4; ++r) {
      float nm = fmaxf(mrun[r], pm[r]);
      scale[r] = __builtin_exp2f(mrun[r] - nm);
      mrun[r] = nm;
    }
    // P = exp2(S - m), row-sum, write bf16 P to per-wave LDS (transpose buffer)
    float rs[4] = {0.f, 0.f, 0.f, 0.f};
#pragma unroll
    for (int kf = 0; kf < 4; ++kf) {
#pragma unroll
      for (int r = 0; r < 4; ++r) {
        float p = __builtin_exp2f(s[kf][r] - mrun[r]);
        rs[r] += p;
        pl[(g * 4 + r) * 72 + kf * 16 + c15] = (bf16)p;
      }
    }
#pragma unroll
    for (int off = 1; off < 16; off <<= 1)
#pragma unroll
      for (int r = 0; r < 4; ++r) rs[r] += __shfl_xor(rs[r], off);
#pragma unroll
    for (int r = 0; r < 4; ++r) lrun[r] = lrun[r] * scale[r] + rs[r];
#pragma unroll
    for (int n = 0; n < 4; ++n)
#pragma unroll
      for (int r = 0; r < 4; ++r) o[n][r] *= scale[r];

    // wave-local LDS fence: P writes must land before A-frag reads
    asm volatile("s_waitcnt lgkmcnt(0)" ::: "memory");

    // O += P @ V   (A-frag: row=c15, k=g*8+j; B-frag from V^T: col=c15, k=g*8+j)
#pragma unroll
    for (int kh = 0; kh < 2; ++kh) {
      const bf16* pp = pl + c15 * 72 + kh * 32 + g * 8;
      bf16x4 plo = *(const bf16x4*)(pp);
      bf16x4 phi = *(const bf16x4*)(pp + 4);
      bf16x8 pa;
#pragma unroll
      for (int j = 0; j < 4; ++j) { pa[j] = plo[j]; pa[4 + j] = phi[j]; }
#pragma unroll
      for (int n = 0; n < 4; ++n) {
        const bf16* Vp = Vbh + (long)(n * 16 + c15) * 2048 + kbase + kh * 32 + g * 8;
        bf16x8 bv = *(const bf16x8*)(Vp);
        o[n] = MFMA16(pa, bv, o[n]);
      }
    }
  }
  // finalize: Aout layout (b, t, h*64+d) bf16 -> feeds out-proj GEMM
  float inv[4];
#pragma unroll
  for (int r = 0; r < 4; ++r) inv[r] = 1.f / lrun[r];
#pragma unroll
  for (int n = 0; n < 4; ++n)
#pragma unroll
    for (int r = 0; r < 4; ++r) {
      long row = (long)b * 2048 + q0 + g * 4 + r;
      Aout[row * 1024 + h * 64 + n * 16 + c15] = (bf16)(o[n][r] * inv[r]);
    }
}

// ---------------- launcher ----------------
extern "C" void kernel_launch(void* const* d_in, const int* in_sizes, int n_in,
                              void* d_out, int out_size, void* d_ws,
                              size_t ws_size, hipStream_t stream) {
  const float* x    = (const float*)d_in[0];
  const int*   mask = (const int*)d_in[1];
  const float* Wqkv = (const float*)d_in[2];
  const float* bqkv = (const float*)d_in[3];
  const float* Wout = (const float*)d_in[4];
  const float* bout = (const float*)d_in[5];
  float* out = (float*)d_out;

  char* ws = (char*)d_ws;
  bf16* xb    = (bf16*)(ws);                      // 8 MB: x bf16 (4096,1024); reused as attn-out
  bf16* wqkvT = (bf16*)(ws + (8u << 20));         // 6 MB: W_qkv^T (3072,1024)
  bf16* woutT = (bf16*)(ws + (14u << 20));        // 2 MB: W_out^T (1024,1024)
  bf16* Qb    = (bf16*)(ws + (16u << 20));        // 8 MB: (b,h,t,d)
  bf16* Kb    = (bf16*)(ws + (24u << 20));        // 8 MB: (b,h,t,d)
  bf16* VTb   = (bf16*)(ws + (32u << 20));        // 8 MB: (b,h,d,t)
  bf16* Aatt  = xb;                               // xb dead after gemm1

  cast_bf16_kernel<<<4096, 256, 0, stream>>>(x, xb, (4096 * 1024) / 4);
  transpose_cast_kernel<<<dim3(48, 16), 256, 0, stream>>>(Wqkv, wqkvT, 1024, 3072);
  transpose_cast_kernel<<<dim3(16, 16), 256, 0, stream>>>(Wout, woutT, 1024, 1024);
  gemm_bt<0><<<dim3(32, 24), 256, 0, stream>>>(xb, wqkvT, bqkv, Qb, Kb, VTb,
                                               nullptr, 1024);
  attn_kernel<<<dim3(32, 32), 256, 0, stream>>>(Qb, Kb, VTb, mask, Aatt);
  gemm_bt<1><<<dim3(32, 8), 256, 0, stream>>>(Aatt, woutT, bout, nullptr,
                                              nullptr, nullptr, out, 1024);
}

// Round 3
// 194.279 us; speedup vs baseline: 1.5859x; 1.5859x over previous
//
#include <hip/hip_runtime.h>

typedef __bf16 bf16;
typedef __bf16 bf16x8 __attribute__((ext_vector_type(8)));
typedef __bf16 bf16x4 __attribute__((ext_vector_type(4)));
typedef float  f32x4  __attribute__((ext_vector_type(4)));
typedef float  f32x16 __attribute__((ext_vector_type(16)));
typedef unsigned int u32x4 __attribute__((ext_vector_type(4)));

#define MFMA16(a, b, c) __builtin_amdgcn_mfma_f32_16x16x32_bf16((a), (b), (c), 0, 0, 0)
#define MFMA32(a, b, c) __builtin_amdgcn_mfma_f32_32x32x16_bf16((a), (b), (c), 0, 0, 0)

// async global->LDS, 16B per lane, LDS dst = wave-uniform base + lane*16
__device__ __forceinline__ void gload_lds16(const bf16* g, bf16* l) {
  __builtin_amdgcn_global_load_lds(
      (const __attribute__((address_space(1))) void*)g,
      (__attribute__((address_space(3))) void*)l, 16, 0, 0);
}

// ---------------- prep kernels ----------------

__global__ __launch_bounds__(256) void cast_bf16_kernel(
    const float* __restrict__ in, bf16* __restrict__ out, int n4) {
  int i = blockIdx.x * 256 + threadIdx.x;
  if (i < n4) {
    float4 v = reinterpret_cast<const float4*>(in)[i];
    bf16x4 o;
    o[0] = (bf16)v.x; o[1] = (bf16)v.y; o[2] = (bf16)v.z; o[3] = (bf16)v.w;
    reinterpret_cast<bf16x4*>(out)[i] = o;
  }
}

__global__ __launch_bounds__(256) void transpose_cast_kernel(
    const float* __restrict__ W, bf16* __restrict__ Wt, int K, int N) {
  __shared__ bf16 tile[64 * 66];
  const int k0 = blockIdx.y * 64, n0 = blockIdx.x * 64;
  const int c = threadIdx.x & 63, rb = threadIdx.x >> 6;
#pragma unroll
  for (int p = 0; p < 16; ++p) {
    int r = p * 4 + rb;
    tile[c * 66 + r] = (bf16)W[(long)(k0 + r) * N + n0 + c];
  }
  __syncthreads();
#pragma unroll
  for (int p = 0; p < 16; ++p) {
    int r = p * 4 + rb;
    Wt[(long)(n0 + r) * K + k0 + c] = tile[r * 66 + c];
  }
}

// ---------------- GEMM: C(M,N) = A(M,K) @ Bt(N,K)^T, m97 structure ----------------
template <int EPI>
__global__ __launch_bounds__(256, 2) void gemm_bt(
    const bf16* __restrict__ A, const bf16* __restrict__ Bt,
    const float* __restrict__ bias, bf16* __restrict__ oQ,
    bf16* __restrict__ oK, bf16* __restrict__ oVT, float* __restrict__ oC,
    int K) {
  __shared__ bf16 As[128 * 64];
  __shared__ bf16 Bs[128 * 64];
  const int tid = threadIdx.x, lane = tid & 63, wid = tid >> 6;
  const int wr = wid >> 1, wc = wid & 1;
  const int brow = blockIdx.x * 128, bcol = blockIdx.y * 128;
  const int srow = lane >> 3, scol8 = (lane & 7) * 8;
  const int c15 = lane & 15, g = lane >> 4;

  f32x4 acc[4][4];
#pragma unroll
  for (int m = 0; m < 4; ++m)
#pragma unroll
    for (int n = 0; n < 4; ++n) acc[m][n] = f32x4{0.f, 0.f, 0.f, 0.f};

  const bf16* Ab = A + (long)brow * K + scol8;
  const bf16* Bb = Bt + (long)bcol * K + scol8;

  for (int k0 = 0; k0 < K; k0 += 64) {
#pragma unroll
    for (int i = 0; i < 4; ++i) {
      int c = wid * 4 + i;
      int row = c * 8 + srow;
      gload_lds16(Ab + (long)row * K + k0, &As[c * 512]);
    }
#pragma unroll
    for (int i = 0; i < 4; ++i) {
      int c = wid * 4 + i;
      int row = c * 8 + srow;
      gload_lds16(Bb + (long)row * K + k0, &Bs[c * 512]);
    }
    __syncthreads();
#pragma unroll
    for (int kk = 0; kk < 64; kk += 32) {
      bf16x8 a[4], b[4];
#pragma unroll
      for (int m = 0; m < 4; ++m)
        a[m] = *(const bf16x8*)&As[(wr * 64 + m * 16 + c15) * 64 + kk + g * 8];
#pragma unroll
      for (int n = 0; n < 4; ++n)
        b[n] = *(const bf16x8*)&Bs[(wc * 64 + n * 16 + c15) * 64 + kk + g * 8];
#pragma unroll
      for (int m = 0; m < 4; ++m)
#pragma unroll
        for (int n = 0; n < 4; ++n)
          acc[m][n] = MFMA16(a[m], b[n], acc[m][n]);
    }
    __syncthreads();
  }

#pragma unroll
  for (int n = 0; n < 4; ++n) {
    const int col = bcol + wc * 64 + n * 16 + c15;
    const float bv = bias[col];
    if (EPI == 0) {
      const int which = col >> 10, wi = col & 1023, h = wi >> 6, d = wi & 63;
      const float sc = (which == 0) ? 0.18033688011112042f : 1.0f;  // 0.125*log2(e)
#pragma unroll
      for (int m = 0; m < 4; ++m) {
        const int row0 = brow + wr * 64 + m * 16 + g * 4;
        const int bb = row0 >> 11, t0 = row0 & 2047;
        const long hb = bb * 16 + h;
        if (which == 2) {
          bf16x4 pv;
#pragma unroll
          for (int r = 0; r < 4; ++r) pv[r] = (bf16)(acc[m][n][r] + bv);
          *(bf16x4*)&oVT[(hb * 64 + d) * 2048 + t0] = pv;  // (b,h,d,t)
        } else {
          bf16* dst = ((which == 0) ? oQ : oK) + (hb * 2048 + t0) * 64 + d;
#pragma unroll
          for (int r = 0; r < 4; ++r)
            dst[(long)r * 64] = (bf16)((acc[m][n][r] + bv) * sc);
        }
      }
    } else {
#pragma unroll
      for (int m = 0; m < 4; ++m) {
        const long row = brow + wr * 64 + m * 16 + g * 4;
#pragma unroll
        for (int r = 0; r < 4; ++r) oC[(row + r) * 1024 + col] = acc[m][n][r] + bv;
      }
    }
  }
}

// ---------------- flash attention, 32x32 swapped-QK^T, in-register softmax ----
// 512 blocks x 4 waves; each wave owns 32 queries, loops 64 KV tiles of 32.
// S^T = mfma32(K, Q): lane(col=query, hi) holds key=(r&3)+8*(r>>2)+4*hi.
// All cross-half (lane^32) exchanges via __shfl_xor (ds_bpermute) --
// direction-unambiguous, unlike v_permlane32_swap whose half-exchange
// orientation was the round-2 correctness bug.
__global__ __launch_bounds__(256, 2) void attn_kernel(
    const bf16* __restrict__ Q, const bf16* __restrict__ K,
    const bf16* __restrict__ VT, const int* __restrict__ mask,
    bf16* __restrict__ Aout) {
  __shared__ float sws[4][32];
  const int tid = threadIdx.x, lane = tid & 63, w = tid >> 6;
  const int col = lane & 31, hi = lane >> 5;
  const int bid = blockIdx.x;
  const int swz = (bid & 7) * 64 + (bid >> 3);  // XCD swizzle: 4 bh per XCD
  const int qt = swz & 15, bh = swz >> 4;
  const int b = bh >> 4, h = bh & 15;
  const int q0 = qt * 128 + w * 32;

  // Q B-frag (pre-scaled by 0.125*log2e in gemm epilogue)
  const bf16* Qp = Q + ((long)bh * 2048 + q0 + col) * 64 + hi * 8;
  bf16x8 bq[4];
#pragma unroll
  for (int dc = 0; dc < 4; ++dc) bq[dc] = *(const bf16x8*)(Qp + dc * 16);

  f32x16 o0, o1;
#pragma unroll
  for (int r = 0; r < 16; ++r) { o0[r] = 0.f; o1[r] = 0.f; }
  float mrun = -1e30f, lrun = 0.f;

  const bf16* Kbh = K + (long)bh * 2048 * 64;
  const bf16* Vbh = VT + (long)bh * 64 * 2048;
  const int* mb = mask + b * 2048;

  auto body = [&](const bf16x8* ak, bf16x8* akn, int t, int tn) {
    const int kbase = t * 32;
    // V loads early (consumed ~200+ cy later by PV)
    bf16x8 bv00, bv01, bv10, bv11;
    {
      const bf16* Vp = Vbh + (long)col * 2048 + kbase + hi * 8;
      bv00 = *(const bf16x8*)(Vp);
      bv10 = *(const bf16x8*)(Vp + 16);
      bv01 = *(const bf16x8*)(Vp + 32 * 2048);
      bv11 = *(const bf16x8*)(Vp + 32 * 2048 + 16);
    }
    // S^T = K @ Q^T
    f32x16 st;
#pragma unroll
    for (int r = 0; r < 16; ++r) st[r] = 0.f;
#pragma unroll
    for (int dc = 0; dc < 4; ++dc) st = MFMA32(ak[dc], bq[dc], st);
    // prefetch next K tile
    {
      const bf16* Kp = Kbh + (long)(tn * 32 + col) * 64 + hi * 8;
#pragma unroll
      for (int dc = 0; dc < 4; ++dc) akn[dc] = *(const bf16x8*)(Kp + dc * 16);
    }
    // mask (wave-uniform skip when all-ones)
    unsigned long long bal = __ballot(mb[kbase + col] != 0);
    unsigned km32 = (unsigned)bal;
    if (km32 != 0xffffffffu) {
      unsigned km = km32 >> (hi * 4);
#pragma unroll
      for (int r = 0; r < 16; ++r)
        if (!((km >> ((r & 3) + 8 * (r >> 2))) & 1)) st[r] = -1e30f;
    }
    // row max: in-lane tree + cross-half exchange (lane^32)
    float m01 = fmaxf(st[0], st[1]), m23 = fmaxf(st[2], st[3]);
    float m45 = fmaxf(st[4], st[5]), m67 = fmaxf(st[6], st[7]);
    float m89 = fmaxf(st[8], st[9]), mab = fmaxf(st[10], st[11]);
    float mcd = fmaxf(st[12], st[13]), mef = fmaxf(st[14], st[15]);
    float m0 = fmaxf(fmaxf(fmaxf(m01, m23), fmaxf(m45, m67)),
                     fmaxf(fmaxf(m89, mab), fmaxf(mcd, mef)));
    float pm = fmaxf(m0, __shfl_xor(m0, 32));
    // defer-max: rescale only when tile max grows past THR=8 (in log2 units)
    if (__any(pm > mrun + 8.0f)) {
      float mnew = fmaxf(mrun, pm);
      float scale = __builtin_exp2f(mrun - mnew);
      mrun = mnew;
      lrun *= scale;
      if (hi == 0) sws[w][col] = scale;  // broadcast q-layout -> d-layout
      asm volatile("s_waitcnt lgkmcnt(0)" ::: "memory");
#pragma unroll
      for (int r = 0; r < 16; ++r) {
        float sc = sws[w][(r & 3) + 8 * (r >> 2) + 4 * hi];
        o0[r] *= sc; o1[r] *= sc;
      }
    }
    // P = exp2(S - m), row-sum (tree)
    float p[16];
#pragma unroll
    for (int r = 0; r < 16; ++r) p[r] = __builtin_exp2f(st[r] - mrun);
    float s01 = p[0] + p[1], s23 = p[2] + p[3], s45 = p[4] + p[5];
    float s67 = p[6] + p[7], s89 = p[8] + p[9], sab = p[10] + p[11];
    float scd = p[12] + p[13], sef = p[14] + p[15];
    float rs = ((s01 + s23) + (s45 + s67)) + ((s89 + sab) + (scd + sef));
    rs += __shfl_xor(rs, 32);
    lrun += rs;
    // P -> bf16 A-frags. Lane (q=col,hi) owns key-pairs:
    //   d0=(0,1)+4hi d1=(2,3)+4hi d2=(8,9)+4hi d3=(10,11)+4hi
    //   d4=(16,17)+4hi d5=(18,19)+4hi d6=(24,25)+4hi d7=(26,27)+4hi
    // A-frag words needed: w0..3 = keys (8hi+0,1)(+2,3)(+4,5)(+6,7), w4..7 same +16.
    // One shfl per word-pair: send (hi ? d_even_lo : d_odd_hi) to partner.
    unsigned d[8];
#pragma unroll
    for (int i = 0; i < 8; ++i) {
      union { bf16 h[2]; unsigned u; } tt;
      tt.h[0] = (bf16)p[2 * i]; tt.h[1] = (bf16)p[2 * i + 1];
      d[i] = tt.u;
    }
    unsigned g02 = (unsigned)__shfl_xor((int)(hi ? d[0] : d[2]), 32);
    unsigned g13 = (unsigned)__shfl_xor((int)(hi ? d[1] : d[3]), 32);
    unsigned g46 = (unsigned)__shfl_xor((int)(hi ? d[4] : d[6]), 32);
    unsigned g57 = (unsigned)__shfl_xor((int)(hi ? d[5] : d[7]), 32);
    u32x4 w0 = {hi ? g02 : d[0], hi ? g13 : d[1], hi ? d[2] : g02, hi ? d[3] : g13};
    u32x4 w1 = {hi ? g46 : d[4], hi ? g57 : d[5], hi ? d[6] : g46, hi ? d[7] : g57};
    bf16x8 pa0 = __builtin_bit_cast(bf16x8, w0);
    bf16x8 pa1 = __builtin_bit_cast(bf16x8, w1);
    // O += P @ V
    o0 = MFMA32(pa0, bv00, o0);
    o0 = MFMA32(pa1, bv10, o0);
    o1 = MFMA32(pa0, bv01, o1);
    o1 = MFMA32(pa1, bv11, o1);
  };

  bf16x8 akA[4], akB[4];
  {
    const bf16* Kp = Kbh + (long)col * 64 + hi * 8;
#pragma unroll
    for (int dc = 0; dc < 4; ++dc) akA[dc] = *(const bf16x8*)(Kp + dc * 16);
  }
  for (int t = 0; t < 64; t += 2) {
    body(akA, akB, t, t + 1);
    body(akB, akA, t + 1, (t + 2 < 64) ? t + 2 : 63);
  }

  // finalize: broadcast 1/lrun q-layout -> d-layout, store (b, t, h*64+d)
  if (hi == 0) sws[w][col] = 1.0f / lrun;
  asm volatile("s_waitcnt lgkmcnt(0)" ::: "memory");
#pragma unroll
  for (int r = 0; r < 16; ++r) {
    const int qr = (r & 3) + 8 * (r >> 2) + 4 * hi;
    float inv = sws[w][qr];
    long base = ((long)b * 2048 + q0 + qr) * 1024 + h * 64 + col;
    Aout[base] = (bf16)(o0[r] * inv);
    Aout[base + 32] = (bf16)(o1[r] * inv);
  }
}

// ---------------- launcher ----------------
extern "C" void kernel_launch(void* const* d_in, const int* in_sizes, int n_in,
                              void* d_out, int out_size, void* d_ws,
                              size_t ws_size, hipStream_t stream) {
  const float* x    = (const float*)d_in[0];
  const int*   mask = (const int*)d_in[1];
  const float* Wqkv = (const float*)d_in[2];
  const float* bqkv = (const float*)d_in[3];
  const float* Wout = (const float*)d_in[4];
  const float* bout = (const float*)d_in[5];
  float* out = (float*)d_out;

  char* ws = (char*)d_ws;
  bf16* xb    = (bf16*)(ws);                      // 8 MB
  bf16* wqkvT = (bf16*)(ws + (8u << 20));         // 6 MB
  bf16* woutT = (bf16*)(ws + (14u << 20));        // 2 MB
  bf16* Qb    = (bf16*)(ws + (16u << 20));        // 8 MB (b,h,t,d)
  bf16* Kb    = (bf16*)(ws + (24u << 20));        // 8 MB (b,h,t,d)
  bf16* VTb   = (bf16*)(ws + (32u << 20));        // 8 MB (b,h,d,t)
  bf16* Aatt  = xb;

  cast_bf16_kernel<<<4096, 256, 0, stream>>>(x, xb, (4096 * 1024) / 4);
  transpose_cast_kernel<<<dim3(48, 16), 256, 0, stream>>>(Wqkv, wqkvT, 1024, 3072);
  transpose_cast_kernel<<<dim3(16, 16), 256, 0, stream>>>(Wout, woutT, 1024, 1024);
  gemm_bt<0><<<dim3(32, 24), 256, 0, stream>>>(xb, wqkvT, bqkv, Qb, Kb, VTb,
                                               nullptr, 1024);
  attn_kernel<<<512, 256, 0, stream>>>(Qb, Kb, VTb, mask, Aatt);
  gemm_bt<1><<<dim3(32, 8), 256, 0, stream>>>(Aatt, woutT, bout, nullptr,
                                              nullptr, nullptr, out, 1024);
}